// Round 1
// 1060.257 us; speedup vs baseline: 1.3717x; 1.3717x over previous
//
#include <hip/hip_runtime.h>

#define NSEG 16
#define CH 128
#define NCOPIES 16  // staging copies in global ws to spread atomic contention
#define WPB 4       // waves per block
#define TILE (NSEG * CH)  // 2048 floats = 8KB per wave-private tile

// ---------------------------------------------------------------------------
// Kernel 1: segment sum + counts. NO LDS ATOMICS.
// Each wave owns a private 8KB LDS tile (4 waves/block -> 32KB LDS -> 5
// blocks/CU). Per iteration a wave processes ONE row: idx is wave-uniform
// (readfirstlane -> SGPR), lane l owns channels [2l,2l+1] exclusively, so the
// accumulate is a plain race-free ds_read_b64/add/ds_write_b64. Counts live in
// a register: lane==idx increments. Next row's loads are issued before the
// current RMW so HBM latency hides under the LDS chain.
// ---------------------------------------------------------------------------
__global__ __launch_bounds__(256) void seg_sum_kernel(
    const float* __restrict__ x, const int* __restrict__ indices,
    float* __restrict__ stage, float* __restrict__ stage_cnt, int N) {
  __shared__ float acc[WPB * TILE];  // exactly 32KB
  const int t = threadIdx.x;
  const int wave = t >> 6;
  const int lane = t & 63;
  float* tile = acc + wave * TILE;

  for (int i = t; i < WPB * TILE; i += 256) acc[i] = 0.f;
  __syncthreads();

  const float2* __restrict__ x2 = (const float2*)x;
  const int stride = gridDim.x * WPB;

  float cntreg = 0.f;  // lane s (s<16) accumulates count for segment s

  int row = blockIdx.x * WPB + wave;
  bool valid = row < N;
  int idx_c = 0;
  float2 v_c = make_float2(0.f, 0.f);
  if (valid) {
    idx_c = indices[row];
    v_c = x2[(long long)row * 64 + lane];
  }
  while (valid) {
    const int nrow = row + stride;
    const bool nvalid = nrow < N;
    int idx_n = 0;
    float2 v_n = make_float2(0.f, 0.f);
    if (nvalid) {  // prefetch next row (wave-uniform branch)
      idx_n = indices[nrow];
      v_n = x2[(long long)nrow * 64 + lane];
    }
    // race-free RMW into wave-private tile
    const int sidx = __builtin_amdgcn_readfirstlane(idx_c);
    float2* a = (float2*)&tile[sidx * CH + lane * 2];
    float2 cur = *a;
    cur.x += v_c.x;
    cur.y += v_c.y;
    *a = cur;
    cntreg += (lane == sidx) ? 1.f : 0.f;

    row = nrow;
    idx_c = idx_n;
    v_c = v_n;
    valid = nvalid;
  }

  const int copy = blockIdx.x & (NCOPIES - 1);
  // counts: one global atomic per wave per segment (tiny, spread over copies)
  if (lane < NSEG) atomicAdd(&stage_cnt[copy * NSEG + lane], cntreg);

  __syncthreads();
  // reduce the 4 wave tiles and push to a staging copy
  float* my_stage = stage + copy * TILE;
  for (int i = t; i < TILE; i += 256) {
    const float s = acc[i] + acc[TILE + i] + acc[2 * TILE + i] + acc[3 * TILE + i];
    atomicAdd(&my_stage[i], s);
  }
}

// ---------------------------------------------------------------------------
// Kernel 2: reduce staging copies -> pooled means -> SE MLP -> gate (16x128).
// Single block; ~131K MACs total, latency a few us.
// ---------------------------------------------------------------------------
__global__ __launch_bounds__(256) void gate_kernel(
    const float* __restrict__ stage, const float* __restrict__ stage_cnt,
    const float* __restrict__ W1, const float* __restrict__ W2,
    float* __restrict__ gate) {
  __shared__ float pooled[NSEG][CH];
  __shared__ float h[NSEG][32];
  __shared__ float cnts[NSEG];
  const int t = threadIdx.x;

  if (t < NSEG) {
    float c = 0.f;
    for (int k = 0; k < NCOPIES; k++) c += stage_cnt[k * NSEG + t];
    cnts[t] = fmaxf(c, 1.f);
  }
  __syncthreads();

  for (int i = t; i < NSEG * CH; i += 256) {
    float s = 0.f;
#pragma unroll
    for (int k = 0; k < NCOPIES; k++) s += stage[k * (NSEG * CH) + i];
    pooled[i >> 7][i & (CH - 1)] = s / cnts[i >> 7];
  }
  __syncthreads();

  // h = relu(pooled @ W1^T); W1 is (32,128) row-major
  for (int o = t; o < NSEG * 32; o += 256) {
    const int s = o >> 5, j = o & 31;
    float sum = 0.f;
#pragma unroll 8
    for (int c = 0; c < CH; c++) sum += pooled[s][c] * W1[j * CH + c];
    h[s][j] = fmaxf(sum, 0.f);
  }
  __syncthreads();

  // gate = sigmoid(h @ W2^T); W2 is (128,32) row-major
  for (int o = t; o < NSEG * CH; o += 256) {
    const int s = o >> 7, c = o & (CH - 1);
    float sum = 0.f;
#pragma unroll
    for (int j = 0; j < 32; j++) sum += h[s][j] * W2[c * 32 + j];
    gate[o] = 1.f / (1.f + expf(-sum));
  }
}

// ---------------------------------------------------------------------------
// Kernel 3: out = x * gate[indices].  Gate staged in 8KB LDS; float4 stream.
// ---------------------------------------------------------------------------
__global__ __launch_bounds__(256) void modulate_kernel(
    const float* __restrict__ x, const int* __restrict__ indices,
    const float* __restrict__ gate, float* __restrict__ out, int N) {
  __shared__ float4 g4[NSEG * 32];
  const int t = threadIdx.x;
  for (int i = t; i < NSEG * 32; i += 256) g4[i] = ((const float4*)gate)[i];
  __syncthreads();

  const float4* __restrict__ x4 = (const float4*)x;
  float4* __restrict__ o4 = (float4*)out;
  const int total = N * 32;  // 32 float4 per row; 32e6 fits int
  const int stride = gridDim.x * 256;
  for (int j = blockIdx.x * 256 + t; j < total; j += stride) {
    const int row = j >> 5;
    const int c4  = j & 31;
    const int idx = indices[row];            // broadcast across 32 lanes
    const float4 v = x4[j];
    const float4 g = g4[idx * 32 + c4];
    float4 r;
    r.x = v.x * g.x;
    r.y = v.y * g.y;
    r.z = v.z * g.z;
    r.w = v.w * g.w;
    o4[j] = r;
  }
}

extern "C" void kernel_launch(void* const* d_in, const int* in_sizes, int n_in,
                              void* d_out, int out_size, void* d_ws, size_t ws_size,
                              hipStream_t stream) {
  const float* x       = (const float*)d_in[0];
  const int*   indices = (const int*)d_in[1];
  const float* W1      = (const float*)d_in[2];
  const float* W2      = (const float*)d_in[3];
  float* out = (float*)d_out;
  const int N = in_sizes[1];

  // ws layout (floats): stage[NCOPIES*2048] | stage_cnt[NCOPIES*16] | gate[2048]
  float* ws        = (float*)d_ws;
  float* stage     = ws;
  float* stage_cnt = stage + NCOPIES * NSEG * CH;
  float* gate      = stage_cnt + NCOPIES * NSEG;

  const size_t zero_bytes =
      (size_t)(NCOPIES * NSEG * CH + NCOPIES * NSEG) * sizeof(float);
  hipMemsetAsync(d_ws, 0, zero_bytes, stream);

  // 5 blocks/CU resident (32KB LDS each), grid-stride over rows
  seg_sum_kernel<<<1280, 256, 0, stream>>>(x, indices, stage, stage_cnt, N);
  gate_kernel<<<1, 256, 0, stream>>>(stage, stage_cnt, W1, W2, gate);
  modulate_kernel<<<4096, 256, 0, stream>>>(x, indices, gate, out, N);
}